// Round 1
// baseline (4002.965 us; speedup 1.0000x reference)
//
#include <hip/hip_runtime.h>
#include <cstdint>
#include <cstddef>

// Problem constants (match reference)
#define BB  4
#define LL  1024
#define DD  1024
#define DIN 2048   // d_inner
#define DS  16     // d_state
#define DC  4      // d_conv
#define DR  64     // dt_rank

enum { EPI_STORE = 0, EPI_ADD = 1, EPI_BIAS_SOFTPLUS = 2 };

__device__ __forceinline__ float softplus_f(float v) {
  return (v > 20.f) ? v : log1pf(expf(v));
}
__device__ __forceinline__ float silu_f(float v) {
  return v / (1.f + expf(-v));
}

// C[M,N] (+)= A[M,K] * B[N,K]^T  (both row-major, K contiguous)
// 128x128 tile, BK=8, 256 threads, 8x8 micro-tile per thread.
template<int EPI>
__global__ __launch_bounds__(256) void gemm_nt(
    const float* __restrict__ A, int lda,
    const float* __restrict__ B, int ldb,
    float* C, int ldc,
    const float* __restrict__ bias,
    int M, int N, int K)
{
  __shared__ __align__(16) float As[8][132];
  __shared__ __align__(16) float Bs[8][132];
  const int tid = threadIdx.x;
  const int m0 = blockIdx.x * 128;
  const int n0 = blockIdx.y * 128;
  const int lr = tid >> 1;          // 0..127
  const int lk = (tid & 1) << 2;    // 0 or 4
  const int ty = tid >> 4;          // 0..15
  const int tx = tid & 15;          // 0..15

  float acc[8][8];
#pragma unroll
  for (int i = 0; i < 8; ++i)
#pragma unroll
    for (int j = 0; j < 8; ++j) acc[i][j] = 0.f;

  const int arow = m0 + lr;
  const int brow = n0 + lr;

  for (int k0 = 0; k0 < K; k0 += 8) {
    float4 av = make_float4(0.f, 0.f, 0.f, 0.f);
    float4 bv = make_float4(0.f, 0.f, 0.f, 0.f);
    if (arow < M) av = *(const float4*)(A + (size_t)arow * lda + k0 + lk);
    if (brow < N) bv = *(const float4*)(B + (size_t)brow * ldb + k0 + lk);
    __syncthreads();  // previous tile fully consumed
    As[lk + 0][lr] = av.x; As[lk + 1][lr] = av.y;
    As[lk + 2][lr] = av.z; As[lk + 3][lr] = av.w;
    Bs[lk + 0][lr] = bv.x; Bs[lk + 1][lr] = bv.y;
    Bs[lk + 2][lr] = bv.z; Bs[lk + 3][lr] = bv.w;
    __syncthreads();
#pragma unroll
    for (int kk = 0; kk < 8; ++kk) {
      float4 a0 = *(const float4*)&As[kk][ty * 8];
      float4 a1 = *(const float4*)&As[kk][ty * 8 + 4];
      float4 b0 = *(const float4*)&Bs[kk][tx * 8];
      float4 b1 = *(const float4*)&Bs[kk][tx * 8 + 4];
      float a[8] = {a0.x, a0.y, a0.z, a0.w, a1.x, a1.y, a1.z, a1.w};
      float b[8] = {b0.x, b0.y, b0.z, b0.w, b1.x, b1.y, b1.z, b1.w};
#pragma unroll
      for (int i = 0; i < 8; ++i)
#pragma unroll
        for (int j = 0; j < 8; ++j)
          acc[i][j] = fmaf(a[i], b[j], acc[i][j]);
    }
  }

#pragma unroll
  for (int i = 0; i < 8; ++i) {
    int r = m0 + ty * 8 + i;
    if (r >= M) continue;
#pragma unroll
    for (int j = 0; j < 8; ++j) {
      int c = n0 + tx * 8 + j;
      if (c >= N) continue;
      float v = acc[i][j];
      size_t off = (size_t)r * ldc + c;
      if (EPI == EPI_ADD) v += C[off];
      if (EPI == EPI_BIAS_SOFTPLUS) v = softplus_f(v + bias[c]);
      C[off] = v;
    }
  }
}

// Causal depthwise conv1d + bias + silu. reverse=0: taps t-3+j w[j];
// reverse=1: taps t+3-j w[j] (flip/conv/flip-back algebra).
__global__ __launch_bounds__(256) void conv_silu_kernel(
    const float* __restrict__ xz,   // [B*L, 4096], xh = cols 0..DIN-1
    const float* __restrict__ w,    // [DIN, 4]
    const float* __restrict__ bias, // [DIN]
    float* __restrict__ xc,         // [B*L, DIN]
    int reverse)
{
  int idx = blockIdx.x * 256 + threadIdx.x;
  if (idx >= BB * LL * DIN) return;
  int d = idx & (DIN - 1);
  int t = (idx >> 11) & (LL - 1);
  int b = idx >> 21;
  const float4 wv = *(const float4*)(w + d * 4);
  const float wj[4] = {wv.x, wv.y, wv.z, wv.w};
  float acc = bias[d];
#pragma unroll
  for (int j = 0; j < 4; ++j) {
    int pos = reverse ? (t + 3 - j) : (t - 3 + j);
    if (pos >= 0 && pos < LL)
      acc = fmaf(xz[(size_t)(b * LL + pos) * 4096 + d], wj[j], acc);
  }
  xc[idx] = silu_f(acc);
}

// Selective scan. 16 lanes per (b,d) channel, one state per lane.
// Fuses y = (scan + u*D) * silu(z). y may alias delta (same-wave
// read-before-write per element, lockstep within the 16-lane group).
__global__ __launch_bounds__(256) void scan_kernel(
    const float* delta,             // [B*L, DIN]  (may alias y)
    const float* __restrict__ xc,   // [B*L, DIN]
    const float* __restrict__ dbc,  // [B*L, 96]: dt|B|C
    const float* __restrict__ xz,   // [B*L, 4096], z = cols DIN..
    const float* __restrict__ A_log,// [DIN, DS]
    const float* __restrict__ Dsk,  // [DIN]
    float* y,                       // [B*L, DIN]
    int reverse)
{
  int tid = threadIdx.x;
  int s = tid & 15;
  int ch = blockIdx.x * 16 + (tid >> 4);  // 0..8191
  int b = ch >> 11;
  int d = ch & (DIN - 1);
  float As = -expf(A_log[d * DS + s]);
  float Dv = Dsk[d];
  float h = 0.f;
  for (int i = 0; i < LL; ++i) {
    int t = reverse ? (LL - 1 - i) : i;
    size_t row = (size_t)b * LL + t;
    float dl = delta[row * DIN + d];
    float u  = xc[row * DIN + d];
    float Bv = dbc[row * 96 + DR + s];
    float Cv = dbc[row * 96 + DR + DS + s];
    float a = expf(dl * As);
    h = fmaf(h, a, (dl * u) * Bv);
    float p = h * Cv;
    p += __shfl_xor(p, 1, 16);
    p += __shfl_xor(p, 2, 16);
    p += __shfl_xor(p, 4, 16);
    p += __shfl_xor(p, 8, 16);
    if (s == 0) {
      float zv = xz[row * 4096 + DIN + d];
      y[row * DIN + d] = (p + u * Dv) * silu_f(zv);
    }
  }
}

// LayerNorm over last dim (1024). One block per row.
__global__ __launch_bounds__(256) void ln_kernel(
    const float* __restrict__ x, const float* __restrict__ accum,
    const float* __restrict__ lnw, const float* __restrict__ lnb,
    float* __restrict__ out)
{
  int row = blockIdx.x;
  int tid = threadIdx.x;
  size_t base = (size_t)row * DD + tid * 4;
  float4 xv = *(const float4*)(x + base);
  float4 av = *(const float4*)(accum + base);
  float h0 = xv.x + av.x, h1 = xv.y + av.y;
  float h2 = xv.z + av.z, h3 = xv.w + av.w;
  float s = h0 + h1 + h2 + h3;
  float q = h0 * h0 + h1 * h1 + h2 * h2 + h3 * h3;
#pragma unroll
  for (int m = 1; m < 64; m <<= 1) {
    s += __shfl_xor(s, m, 64);
    q += __shfl_xor(q, m, 64);
  }
  __shared__ float rs[4], rq[4];
  int wid = tid >> 6;
  if ((tid & 63) == 0) { rs[wid] = s; rq[wid] = q; }
  __syncthreads();
  s = rs[0] + rs[1] + rs[2] + rs[3];
  q = rq[0] + rq[1] + rq[2] + rq[3];
  float mu = s * (1.f / DD);
  float var = q * (1.f / DD) - mu * mu;
  float rstd = rsqrtf(var + 1e-5f);
  float4 w  = *(const float4*)(lnw + tid * 4);
  float4 bv = *(const float4*)(lnb + tid * 4);
  float4 o;
  o.x = (h0 - mu) * rstd * w.x + bv.x;
  o.y = (h1 - mu) * rstd * w.y + bv.y;
  o.z = (h2 - mu) * rstd * w.z + bv.z;
  o.w = (h3 - mu) * rstd * w.w + bv.w;
  *(float4*)(out + base) = o;
}

extern "C" void kernel_launch(void* const* d_in, const int* in_sizes, int n_in,
                              void* d_out, int out_size, void* d_ws, size_t ws_size,
                              hipStream_t stream) {
  const float* x = (const float*)d_in[0];
  // per-direction params: 0 in_proj,1 conv_w,2 conv_b,3 x_proj,4 dt_w,
  // 5 dt_b,6 A_log,7 D,8 out_proj
  const float* P[2][9];
  for (int dir = 0; dir < 2; ++dir)
    for (int j = 0; j < 9; ++j)
      P[dir][j] = (const float*)d_in[1 + dir * 9 + j];
  const float* ln_w = (const float*)d_in[19];
  const float* ln_b = (const float*)d_in[20];
  float* out = (float*)d_out;

  // Workspace layout (floats). Total 37M floats = 155.2 MB.
  const size_t F = 1024 * 1024;
  float* ws    = (float*)d_ws;
  float* XZ    = ws;            // [4096,4096]  16M  (xh | z)
  float* XC    = ws + 16 * F;   // [4096,2048]   8M
  float* DBC   = ws + 24 * F;   // [4096,96]     (1M slot)
  float* DELTA = ws + 25 * F;   // [4096,2048]   8M   (aliased as Y by scan)
  float* ACC   = ws + 33 * F;   // [4096,1024]   4M

  const int MROWS = BB * LL;  // 4096

  for (int dir = 0; dir < 2; ++dir) {
    const float* in_proj  = P[dir][0];
    const float* conv_w   = P[dir][1];
    const float* conv_b   = P[dir][2];
    const float* x_proj   = P[dir][3];
    const float* dt_w     = P[dir][4];
    const float* dt_b     = P[dir][5];
    const float* A_log    = P[dir][6];
    const float* Dsk      = P[dir][7];
    const float* out_proj = P[dir][8];

    // xz = x @ in_proj.T : [4096,1024]x[1024,4096]
    gemm_nt<EPI_STORE><<<dim3(32, 32), 256, 0, stream>>>(
        x, DD, in_proj, DD, XZ, 2 * DIN, nullptr, MROWS, 2 * DIN, DD);

    // conv + silu
    conv_silu_kernel<<<(BB * LL * DIN) / 256, 256, 0, stream>>>(
        XZ, conv_w, conv_b, XC, dir);

    // dbc = xc @ x_proj.T : [4096,2048]x[2048,96]
    gemm_nt<EPI_STORE><<<dim3(32, 1), 256, 0, stream>>>(
        XC, DIN, x_proj, DIN, DBC, 96, nullptr, MROWS, DR + 2 * DS, DIN);

    // delta = softplus(dt @ dt_w.T + dt_b) : [4096,64]x[64,2048]
    gemm_nt<EPI_BIAS_SOFTPLUS><<<dim3(32, 16), 256, 0, stream>>>(
        DBC, 96, dt_w, DR, DELTA, DIN, dt_b, MROWS, DIN, DR);

    // selective scan + gating (Y aliases DELTA)
    scan_kernel<<<512, 256, 0, stream>>>(
        DELTA, XC, DBC, XZ, A_log, Dsk, DELTA, dir);

    // out accum (+)= y @ out_proj.T : [4096,2048]x[2048,1024]
    if (dir == 0)
      gemm_nt<EPI_STORE><<<dim3(32, 8), 256, 0, stream>>>(
          DELTA, DIN, out_proj, DIN, ACC, DD, nullptr, MROWS, DD, DIN);
    else
      gemm_nt<EPI_ADD><<<dim3(32, 8), 256, 0, stream>>>(
          DELTA, DIN, out_proj, DIN, ACC, DD, nullptr, MROWS, DD, DIN);
  }

  // LayerNorm(x + yf + yb)
  ln_kernel<<<MROWS, 256, 0, stream>>>(x, ACC, ln_w, ln_b, out);
}

// Round 4
// 2768.072 us; speedup vs baseline: 1.4461x; 1.4461x over previous
//
#include <hip/hip_runtime.h>
#include <cstdint>
#include <cstddef>

// Problem constants (match reference)
#define BB  4
#define LL  1024
#define DD  1024
#define DIN 2048   // d_inner
#define DS  16     // d_state
#define DC  4      // d_conv
#define DR  64     // dt_rank

typedef unsigned short ushort_t;
typedef __attribute__((ext_vector_type(8))) short bf16x8;
typedef __attribute__((ext_vector_type(4))) float f32x4;
typedef __attribute__((ext_vector_type(4))) unsigned short us4;

enum { EPI_STORE = 0, EPI_ADD = 1, EPI_BIAS_SOFTPLUS = 2 };

__device__ __forceinline__ float softplus_f(float v) {
  return (v > 20.f) ? v : log1pf(expf(v));
}
__device__ __forceinline__ float silu_f(float v) {
  return v / (1.f + expf(-v));
}
__device__ __forceinline__ ushort_t f32_to_bf16(float f) {
  uint32_t u = __float_as_uint(f);
  uint32_t r = (u + 0x7FFFu + ((u >> 16) & 1u)) >> 16;  // RNE
  return (ushort_t)r;
}

// async global->LDS, 16 bytes per lane (dest must be wave-uniform base + lane*16)
__device__ __forceinline__ void async_copy16(const void* g, void* lds) {
  __builtin_amdgcn_global_load_lds(
      (const __attribute__((address_space(1))) unsigned int*)g,
      (__attribute__((address_space(3))) unsigned int*)lds, 16, 0, 0);
}

// f32 -> bf16 cast, 4 elems/thread
__global__ __launch_bounds__(256) void cast_bf16_kernel(
    const float* __restrict__ src, ushort_t* __restrict__ dst, int n)
{
  int i = (blockIdx.x * 256 + threadIdx.x) * 4;
  if (i >= n) return;
  float4 v = *(const float4*)(src + i);
  us4 o = { f32_to_bf16(v.x), f32_to_bf16(v.y), f32_to_bf16(v.z), f32_to_bf16(v.w) };
  *(us4*)(dst + i) = o;
}

// ---------------------------------------------------------------------------
// bf16 MFMA GEMM (m97 structure): C[M,N] (+)= A[M,K] * B[N,K]^T
// A,B bf16 row-major (K contiguous), C f32. M,N multiples of 128, K of 32.
// 128x128 tile, BK=32, 256 threads = 4 waves (2x2), 64x64 per wave.
// ---------------------------------------------------------------------------
template<int EPI>
__global__ __launch_bounds__(256) void gemm_nt_mfma(
    const ushort_t* __restrict__ A, int lda,
    const ushort_t* __restrict__ B, int ldb,
    float* C, int ldc, int K)
{
  __shared__ __align__(16) ushort_t As[128 * 32];
  __shared__ __align__(16) ushort_t Bs[128 * 32];
  const int tid  = threadIdx.x;
  const int lane = tid & 63;
  const int wave = tid >> 6;            // 0..3
  const int wm = (wave & 1) * 64;
  const int wn = (wave >> 1) * 64;
  const int m0 = blockIdx.x * 128;
  const int n0 = blockIdx.y * 128;
  const int lr = lane & 15;             // fragment row within 16
  const int lk = (lane >> 4) * 8;       // fragment k offset (8 bf16 = 16 B)

  f32x4 acc[4][4];
#pragma unroll
  for (int i = 0; i < 4; ++i)
#pragma unroll
    for (int j = 0; j < 4; ++j) acc[i][j] = (f32x4){0.f, 0.f, 0.f, 0.f};

  for (int k0 = 0; k0 < K; k0 += 32) {
    __syncthreads();  // all waves done reading previous tile
    // stage 128x32 bf16 tiles of A and B: 512 chunks x 16 B each
#pragma unroll
    for (int it = 0; it < 2; ++it) {
      int c  = tid + it * 256;
      int r  = c >> 2;
      int cb = (c & 3) << 3;  // col offset in ushort units
      async_copy16(A + (size_t)(m0 + r) * lda + k0 + cb, (char*)As + c * 16);
      async_copy16(B + (size_t)(n0 + r) * ldb + k0 + cb, (char*)Bs + c * 16);
    }
    __syncthreads();  // vmcnt(0) drained by compiler -> tile ready

    bf16x8 a_frag[4], b_frag[4];
#pragma unroll
    for (int i = 0; i < 4; ++i)
      a_frag[i] = *(const bf16x8*)&As[(wm + i * 16 + lr) * 32 + lk];
#pragma unroll
    for (int j = 0; j < 4; ++j)
      b_frag[j] = *(const bf16x8*)&Bs[(wn + j * 16 + lr) * 32 + lk];
#pragma unroll
    for (int i = 0; i < 4; ++i)
#pragma unroll
      for (int j = 0; j < 4; ++j)
        acc[i][j] = __builtin_amdgcn_mfma_f32_16x16x32_bf16(
            a_frag[i], b_frag[j], acc[i][j], 0, 0, 0);
  }

  // C/D layout: row = (lane>>4)*4 + reg (1st operand dim), col = lane&15 (2nd)
  const int rbase = m0 + wm + (lane >> 4) * 4;
  const int cbase = n0 + wn + (lane & 15);
#pragma unroll
  for (int i = 0; i < 4; ++i)
#pragma unroll
    for (int j = 0; j < 4; ++j)
#pragma unroll
      for (int r = 0; r < 4; ++r) {
        size_t off = (size_t)(rbase + i * 16 + r) * ldc + cbase + j * 16;
        float v = acc[i][j][r];
        if (EPI == EPI_ADD) v += C[off];
        C[off] = v;
      }
}

// ---------------------------------------------------------------------------
// f32 vector GEMM (for small GEMM2/GEMM3): C[M,N] (+)= A[M,K] * B[N,K]^T
// ---------------------------------------------------------------------------
template<int EPI>
__global__ __launch_bounds__(256) void gemm_nt(
    const float* __restrict__ A, int lda,
    const float* __restrict__ B, int ldb,
    float* C, int ldc,
    const float* __restrict__ bias,
    int M, int N, int K)
{
  __shared__ __align__(16) float As[8][132];
  __shared__ __align__(16) float Bs[8][132];
  const int tid = threadIdx.x;
  const int m0 = blockIdx.x * 128;
  const int n0 = blockIdx.y * 128;
  const int lr = tid >> 1;
  const int lk = (tid & 1) << 2;
  const int ty = tid >> 4;
  const int tx = tid & 15;

  float acc[8][8];
#pragma unroll
  for (int i = 0; i < 8; ++i)
#pragma unroll
    for (int j = 0; j < 8; ++j) acc[i][j] = 0.f;

  const int arow = m0 + lr;
  const int brow = n0 + lr;

  for (int k0 = 0; k0 < K; k0 += 8) {
    float4 av = make_float4(0.f, 0.f, 0.f, 0.f);
    float4 bv = make_float4(0.f, 0.f, 0.f, 0.f);
    if (arow < M) av = *(const float4*)(A + (size_t)arow * lda + k0 + lk);
    if (brow < N) bv = *(const float4*)(B + (size_t)brow * ldb + k0 + lk);
    __syncthreads();
    As[lk + 0][lr] = av.x; As[lk + 1][lr] = av.y;
    As[lk + 2][lr] = av.z; As[lk + 3][lr] = av.w;
    Bs[lk + 0][lr] = bv.x; Bs[lk + 1][lr] = bv.y;
    Bs[lk + 2][lr] = bv.z; Bs[lk + 3][lr] = bv.w;
    __syncthreads();
#pragma unroll
    for (int kk = 0; kk < 8; ++kk) {
      float4 a0 = *(const float4*)&As[kk][ty * 8];
      float4 a1 = *(const float4*)&As[kk][ty * 8 + 4];
      float4 b0 = *(const float4*)&Bs[kk][tx * 8];
      float4 b1 = *(const float4*)&Bs[kk][tx * 8 + 4];
      float a[8] = {a0.x, a0.y, a0.z, a0.w, a1.x, a1.y, a1.z, a1.w};
      float b[8] = {b0.x, b0.y, b0.z, b0.w, b1.x, b1.y, b1.z, b1.w};
#pragma unroll
      for (int i = 0; i < 8; ++i)
#pragma unroll
        for (int j = 0; j < 8; ++j)
          acc[i][j] = fmaf(a[i], b[j], acc[i][j]);
    }
  }

#pragma unroll
  for (int i = 0; i < 8; ++i) {
    int r = m0 + ty * 8 + i;
    if (r >= M) continue;
#pragma unroll
    for (int j = 0; j < 8; ++j) {
      int c = n0 + tx * 8 + j;
      if (c >= N) continue;
      float v = acc[i][j];
      size_t off = (size_t)r * ldc + c;
      if (EPI == EPI_ADD) v += C[off];
      if (EPI == EPI_BIAS_SOFTPLUS) v = softplus_f(v + bias[c]);
      C[off] = v;
    }
  }
}

// Causal depthwise conv1d + bias + silu. reverse=0: taps t-3+j w[j];
// reverse=1: taps t+3-j w[j] (flip/conv/flip-back algebra).
__global__ __launch_bounds__(256) void conv_silu_kernel(
    const float* __restrict__ xz,   // [B*L, 4096], xh = cols 0..DIN-1
    const float* __restrict__ w,    // [DIN, 4]
    const float* __restrict__ bias, // [DIN]
    float* __restrict__ xc,         // [B*L, DIN]
    int reverse)
{
  int idx = blockIdx.x * 256 + threadIdx.x;
  if (idx >= BB * LL * DIN) return;
  int d = idx & (DIN - 1);
  int t = (idx >> 11) & (LL - 1);
  int b = idx >> 21;
  const float4 wv = *(const float4*)(w + d * 4);
  const float wj[4] = {wv.x, wv.y, wv.z, wv.w};
  float acc = bias[d];
#pragma unroll
  for (int j = 0; j < 4; ++j) {
    int pos = reverse ? (t + 3 - j) : (t - 3 + j);
    if (pos >= 0 && pos < LL)
      acc = fmaf(xz[(size_t)(b * LL + pos) * 4096 + d], wj[j], acc);
  }
  xc[idx] = silu_f(acc);
}

// Selective scan. 16 lanes per (b,d) channel, one state per lane.
// Fuses y = (scan + u*D) * silu(z); emits y as bf16 for the MFMA out-GEMM.
__global__ __launch_bounds__(256) void scan_kernel(
    const float* __restrict__ delta, // [B*L, DIN]
    const float* __restrict__ xc,    // [B*L, DIN]
    const float* __restrict__ dbc,   // [B*L, 96]: dt|B|C
    const float* __restrict__ xz,    // [B*L, 4096], z = cols DIN..
    const float* __restrict__ A_log, // [DIN, DS]
    const float* __restrict__ Dsk,   // [DIN]
    ushort_t* __restrict__ ybf,      // [B*L, DIN] bf16
    int reverse)
{
  int tid = threadIdx.x;
  int s = tid & 15;
  int ch = blockIdx.x * 16 + (tid >> 4);  // 0..8191
  int b = ch >> 11;
  int d = ch & (DIN - 1);
  float As = -expf(A_log[d * DS + s]);
  float Dv = Dsk[d];
  float h = 0.f;
  for (int i = 0; i < LL; ++i) {
    int t = reverse ? (LL - 1 - i) : i;
    size_t row = (size_t)b * LL + t;
    float dl = delta[row * DIN + d];
    float u  = xc[row * DIN + d];
    float Bv = dbc[row * 96 + DR + s];
    float Cv = dbc[row * 96 + DR + DS + s];
    float a = expf(dl * As);
    h = fmaf(h, a, (dl * u) * Bv);
    float p = h * Cv;
    p += __shfl_xor(p, 1, 16);
    p += __shfl_xor(p, 2, 16);
    p += __shfl_xor(p, 4, 16);
    p += __shfl_xor(p, 8, 16);
    if (s == 0) {
      float zv = xz[row * 4096 + DIN + d];
      ybf[row * DIN + d] = f32_to_bf16((p + u * Dv) * silu_f(zv));
    }
  }
}

// LayerNorm over last dim (1024). One block per row.
__global__ __launch_bounds__(256) void ln_kernel(
    const float* __restrict__ x, const float* __restrict__ accum,
    const float* __restrict__ lnw, const float* __restrict__ lnb,
    float* __restrict__ out)
{
  int row = blockIdx.x;
  int tid = threadIdx.x;
  size_t base = (size_t)row * DD + tid * 4;
  float4 xv = *(const float4*)(x + base);
  float4 av = *(const float4*)(accum + base);
  float h0 = xv.x + av.x, h1 = xv.y + av.y;
  float h2 = xv.z + av.z, h3 = xv.w + av.w;
  float s = h0 + h1 + h2 + h3;
  float q = h0 * h0 + h1 * h1 + h2 * h2 + h3 * h3;
#pragma unroll
  for (int m = 1; m < 64; m <<= 1) {
    s += __shfl_xor(s, m, 64);
    q += __shfl_xor(q, m, 64);
  }
  __shared__ float rs[4], rq[4];
  int wid = tid >> 6;
  if ((tid & 63) == 0) { rs[wid] = s; rq[wid] = q; }
  __syncthreads();
  s = rs[0] + rs[1] + rs[2] + rs[3];
  q = rq[0] + rq[1] + rq[2] + rq[3];
  float mu = s * (1.f / DD);
  float var = q * (1.f / DD) - mu * mu;
  float rstd = rsqrtf(var + 1e-5f);
  float4 w  = *(const float4*)(lnw + tid * 4);
  float4 bv = *(const float4*)(lnb + tid * 4);
  float4 o;
  o.x = (h0 - mu) * rstd * w.x + bv.x;
  o.y = (h1 - mu) * rstd * w.y + bv.y;
  o.z = (h2 - mu) * rstd * w.z + bv.z;
  o.w = (h3 - mu) * rstd * w.w + bv.w;
  *(float4*)(out + base) = o;
}

extern "C" void kernel_launch(void* const* d_in, const int* in_sizes, int n_in,
                              void* d_out, int out_size, void* d_ws, size_t ws_size,
                              hipStream_t stream) {
  const float* x = (const float*)d_in[0];
  const float* P[2][9];
  for (int dir = 0; dir < 2; ++dir)
    for (int j = 0; j < 9; ++j)
      P[dir][j] = (const float*)d_in[1 + dir * 9 + j];
  const float* ln_w = (const float*)d_in[19];
  const float* ln_b = (const float*)d_in[20];
  float* out = (float*)d_out;
  (void)ws_size;

  // Workspace layout (floats). Total 44M floats = 176 MB.
  const size_t F = 1024 * 1024;
  float* ws      = (float*)d_ws;
  float*    XZ   = ws;                       // [4096,4096] f32  16M (xh|z)
  float*    XC   = ws + 16 * F;              // [4096,2048] f32   8M
  float*    DBC  = ws + 24 * F;              // [4096,96]   f32  (1M slot)
  float*    DELTA= ws + 25 * F;              // [4096,2048] f32   8M
  float*    ACC  = ws + 33 * F;              // [4096,1024] f32   4M
  ushort_t* XBF  = (ushort_t*)(ws + 37 * F); // [4096,1024] bf16 (2M f32)
  ushort_t* WBF  = (ushort_t*)(ws + 39 * F); // 8M ushort slot: in_proj_bf / YBF
  ushort_t* OPBF = (ushort_t*)(ws + 43 * F); // [1024,2048] bf16 (1M f32)

  const int MROWS = BB * LL;  // 4096

  // x -> bf16 once
  cast_bf16_kernel<<<(MROWS * DD) / 1024, 256, 0, stream>>>(x, XBF, MROWS * DD);

  for (int dir = 0; dir < 2; ++dir) {
    const float* in_proj  = P[dir][0];
    const float* conv_w   = P[dir][1];
    const float* conv_b   = P[dir][2];
    const float* x_proj   = P[dir][3];
    const float* dt_w     = P[dir][4];
    const float* dt_b     = P[dir][5];
    const float* A_log    = P[dir][6];
    const float* Dsk      = P[dir][7];
    const float* out_proj = P[dir][8];

    // weights -> bf16
    cast_bf16_kernel<<<(2 * DIN * DD) / 1024, 256, 0, stream>>>(
        in_proj, WBF, 2 * DIN * DD);
    cast_bf16_kernel<<<(DD * DIN) / 1024, 256, 0, stream>>>(
        out_proj, OPBF, DD * DIN);

    // xz = x @ in_proj.T : [4096,1024] x [4096,1024]^T -> [4096,4096]
    gemm_nt_mfma<EPI_STORE><<<dim3(32, 32), 256, 0, stream>>>(
        XBF, DD, WBF, DD, XZ, 2 * DIN, DD);

    // conv + silu
    conv_silu_kernel<<<(BB * LL * DIN) / 256, 256, 0, stream>>>(
        XZ, conv_w, conv_b, XC, dir);

    // dbc = xc @ x_proj.T : [4096,2048] x [96,2048]^T (f32)
    gemm_nt<EPI_STORE><<<dim3(32, 1), 256, 0, stream>>>(
        XC, DIN, x_proj, DIN, DBC, 96, nullptr, MROWS, DR + 2 * DS, DIN);

    // delta = softplus(dt @ dt_w.T + dt_b) : [4096,64] x [2048,64]^T (f32)
    gemm_nt<EPI_BIAS_SOFTPLUS><<<dim3(32, 16), 256, 0, stream>>>(
        DBC, 96, dt_w, DR, DELTA, DIN, dt_b, MROWS, DIN, DR);

    // selective scan + gating -> y (bf16) into WBF (in_proj_bf is dead)
    scan_kernel<<<512, 256, 0, stream>>>(
        DELTA, XC, DBC, XZ, A_log, Dsk, WBF, dir);

    // out accum (+)= y @ out_proj.T : [4096,2048] x [1024,2048]^T
    if (dir == 0)
      gemm_nt_mfma<EPI_STORE><<<dim3(32, 8), 256, 0, stream>>>(
          WBF, DIN, OPBF, DIN, ACC, DD, DIN);
    else
      gemm_nt_mfma<EPI_ADD><<<dim3(32, 8), 256, 0, stream>>>(
          WBF, DIN, OPBF, DIN, ACC, DD, DIN);
  }

  // LayerNorm(x + yf + yb)
  ln_kernel<<<MROWS, 256, 0, stream>>>(x, ACC, ln_w, ln_b, out);
}

// Round 7
// 1752.277 us; speedup vs baseline: 2.2844x; 1.5797x over previous
//
#include <hip/hip_runtime.h>
#include <cstdint>
#include <cstddef>

// Problem constants (match reference)
#define BB  4
#define LL  1024
#define DD  1024
#define DIN 2048   // d_inner
#define DS  16     // d_state
#define DC  4      // d_conv
#define DR  64     // dt_rank

typedef unsigned short ushort_t;
typedef __attribute__((ext_vector_type(8))) short bf16x8;
typedef __attribute__((ext_vector_type(4))) float f32x4;
typedef __attribute__((ext_vector_type(4))) unsigned short us4;

enum { EPI_STORE = 0, EPI_ADD = 1, EPI_BIAS_SOFTPLUS = 2 };

__device__ __forceinline__ float softplus_f(float v) {
  return (v > 20.f) ? v : log1pf(expf(v));
}
__device__ __forceinline__ float silu_f(float v) {
  return v / (1.f + expf(-v));
}
__device__ __forceinline__ ushort_t f32_to_bf16(float f) {
  uint32_t u = __float_as_uint(f);
  uint32_t r = (u + 0x7FFFu + ((u >> 16) & 1u)) >> 16;  // RNE
  return (ushort_t)r;
}

// async global->LDS, 16 bytes per lane (dest must be wave-uniform base + lane*16)
__device__ __forceinline__ void async_copy16(const void* g, void* lds) {
  __builtin_amdgcn_global_load_lds(
      (const __attribute__((address_space(1))) unsigned int*)g,
      (__attribute__((address_space(3))) unsigned int*)lds, 16, 0, 0);
}

// f32 -> bf16 cast, 4 elems/thread
__global__ __launch_bounds__(256) void cast_bf16_kernel(
    const float* __restrict__ src, ushort_t* __restrict__ dst, int n)
{
  int i = (blockIdx.x * 256 + threadIdx.x) * 4;
  if (i >= n) return;
  float4 v = *(const float4*)(src + i);
  us4 o = { f32_to_bf16(v.x), f32_to_bf16(v.y), f32_to_bf16(v.z), f32_to_bf16(v.w) };
  *(us4*)(dst + i) = o;
}

// ---------------------------------------------------------------------------
// bf16 MFMA GEMM (m97 structure): C[M,N] (+)= A[M,K] * B[N,K]^T
// A,B bf16 row-major (K contiguous), C f32. M,N multiples of 128, K of 32.
// 128x128 tile, BK=32, 256 threads = 4 waves (2x2), 64x64 per wave.
// ---------------------------------------------------------------------------
template<int EPI>
__global__ __launch_bounds__(256) void gemm_nt_mfma(
    const ushort_t* __restrict__ A, int lda,
    const ushort_t* __restrict__ B, int ldb,
    float* C, int ldc, int K)
{
  __shared__ __align__(16) ushort_t As[128 * 32];
  __shared__ __align__(16) ushort_t Bs[128 * 32];
  const int tid  = threadIdx.x;
  const int lane = tid & 63;
  const int wave = tid >> 6;            // 0..3
  const int wm = (wave & 1) * 64;
  const int wn = (wave >> 1) * 64;
  const int m0 = blockIdx.x * 128;
  const int n0 = blockIdx.y * 128;
  const int lr = lane & 15;             // fragment row within 16
  const int lk = (lane >> 4) * 8;       // fragment k offset (8 bf16 = 16 B)

  f32x4 acc[4][4];
#pragma unroll
  for (int i = 0; i < 4; ++i)
#pragma unroll
    for (int j = 0; j < 4; ++j) acc[i][j] = (f32x4){0.f, 0.f, 0.f, 0.f};

  for (int k0 = 0; k0 < K; k0 += 32) {
    __syncthreads();  // all waves done reading previous tile
    // stage 128x32 bf16 tiles of A and B: 512 chunks x 16 B each
#pragma unroll
    for (int it = 0; it < 2; ++it) {
      int c  = tid + it * 256;
      int r  = c >> 2;
      int cb = (c & 3) << 3;  // col offset in ushort units
      async_copy16(A + (size_t)(m0 + r) * lda + k0 + cb, (char*)As + c * 16);
      async_copy16(B + (size_t)(n0 + r) * ldb + k0 + cb, (char*)Bs + c * 16);
    }
    __syncthreads();  // vmcnt(0) drained by compiler -> tile ready

    bf16x8 a_frag[4], b_frag[4];
#pragma unroll
    for (int i = 0; i < 4; ++i)
      a_frag[i] = *(const bf16x8*)&As[(wm + i * 16 + lr) * 32 + lk];
#pragma unroll
    for (int j = 0; j < 4; ++j)
      b_frag[j] = *(const bf16x8*)&Bs[(wn + j * 16 + lr) * 32 + lk];
#pragma unroll
    for (int i = 0; i < 4; ++i)
#pragma unroll
      for (int j = 0; j < 4; ++j)
        acc[i][j] = __builtin_amdgcn_mfma_f32_16x16x32_bf16(
            a_frag[i], b_frag[j], acc[i][j], 0, 0, 0);
  }

  // C/D layout: row = (lane>>4)*4 + reg (1st operand dim), col = lane&15 (2nd)
  const int rbase = m0 + wm + (lane >> 4) * 4;
  const int cbase = n0 + wn + (lane & 15);
#pragma unroll
  for (int i = 0; i < 4; ++i)
#pragma unroll
    for (int j = 0; j < 4; ++j)
#pragma unroll
      for (int r = 0; r < 4; ++r) {
        size_t off = (size_t)(rbase + i * 16 + r) * ldc + cbase + j * 16;
        float v = acc[i][j][r];
        if (EPI == EPI_ADD) v += C[off];
        C[off] = v;
      }
}

// ---------------------------------------------------------------------------
// f32 vector GEMM (for small GEMM2/GEMM3): C[M,N] (+)= A[M,K] * B[N,K]^T
// ---------------------------------------------------------------------------
template<int EPI>
__global__ __launch_bounds__(256) void gemm_nt(
    const float* __restrict__ A, int lda,
    const float* __restrict__ B, int ldb,
    float* C, int ldc,
    const float* __restrict__ bias,
    int M, int N, int K)
{
  __shared__ __align__(16) float As[8][132];
  __shared__ __align__(16) float Bs[8][132];
  const int tid = threadIdx.x;
  const int m0 = blockIdx.x * 128;
  const int n0 = blockIdx.y * 128;
  const int lr = tid >> 1;
  const int lk = (tid & 1) << 2;
  const int ty = tid >> 4;
  const int tx = tid & 15;

  float acc[8][8];
#pragma unroll
  for (int i = 0; i < 8; ++i)
#pragma unroll
    for (int j = 0; j < 8; ++j) acc[i][j] = 0.f;

  const int arow = m0 + lr;
  const int brow = n0 + lr;

  for (int k0 = 0; k0 < K; k0 += 8) {
    float4 av = make_float4(0.f, 0.f, 0.f, 0.f);
    float4 bv = make_float4(0.f, 0.f, 0.f, 0.f);
    if (arow < M) av = *(const float4*)(A + (size_t)arow * lda + k0 + lk);
    if (brow < N) bv = *(const float4*)(B + (size_t)brow * ldb + k0 + lk);
    __syncthreads();
    As[lk + 0][lr] = av.x; As[lk + 1][lr] = av.y;
    As[lk + 2][lr] = av.z; As[lk + 3][lr] = av.w;
    Bs[lk + 0][lr] = bv.x; Bs[lk + 1][lr] = bv.y;
    Bs[lk + 2][lr] = bv.z; Bs[lk + 3][lr] = bv.w;
    __syncthreads();
#pragma unroll
    for (int kk = 0; kk < 8; ++kk) {
      float4 a0 = *(const float4*)&As[kk][ty * 8];
      float4 a1 = *(const float4*)&As[kk][ty * 8 + 4];
      float4 b0 = *(const float4*)&Bs[kk][tx * 8];
      float4 b1 = *(const float4*)&Bs[kk][tx * 8 + 4];
      float a[8] = {a0.x, a0.y, a0.z, a0.w, a1.x, a1.y, a1.z, a1.w};
      float b[8] = {b0.x, b0.y, b0.z, b0.w, b1.x, b1.y, b1.z, b1.w};
#pragma unroll
      for (int i = 0; i < 8; ++i)
#pragma unroll
        for (int j = 0; j < 8; ++j)
          acc[i][j] = fmaf(a[i], b[j], acc[i][j]);
    }
  }

#pragma unroll
  for (int i = 0; i < 8; ++i) {
    int r = m0 + ty * 8 + i;
    if (r >= M) continue;
#pragma unroll
    for (int j = 0; j < 8; ++j) {
      int c = n0 + tx * 8 + j;
      if (c >= N) continue;
      float v = acc[i][j];
      size_t off = (size_t)r * ldc + c;
      if (EPI == EPI_ADD) v += C[off];
      if (EPI == EPI_BIAS_SOFTPLUS) v = softplus_f(v + bias[c]);
      C[off] = v;
    }
  }
}

// Causal depthwise conv1d + bias + silu. reverse=0: taps t-3+j w[j];
// reverse=1: taps t+3-j w[j] (flip/conv/flip-back algebra).
__global__ __launch_bounds__(256) void conv_silu_kernel(
    const float* __restrict__ xz,   // [B*L, 4096], xh = cols 0..DIN-1
    const float* __restrict__ w,    // [DIN, 4]
    const float* __restrict__ bias, // [DIN]
    float* __restrict__ xc,         // [B*L, DIN]
    int reverse)
{
  int idx = blockIdx.x * 256 + threadIdx.x;
  if (idx >= BB * LL * DIN) return;
  int d = idx & (DIN - 1);
  int t = (idx >> 11) & (LL - 1);
  int b = idx >> 21;
  const float4 wv = *(const float4*)(w + d * 4);
  const float wj[4] = {wv.x, wv.y, wv.z, wv.w};
  float acc = bias[d];
#pragma unroll
  for (int j = 0; j < 4; ++j) {
    int pos = reverse ? (t + 3 - j) : (t - 3 + j);
    if (pos >= 0 && pos < LL)
      acc = fmaf(xz[(size_t)(b * LL + pos) * 4096 + d], wj[j], acc);
  }
  xc[idx] = silu_f(acc);
}

// ---------------------------------------------------------------------------
// Selective scan, ILP-unrolled: 16 lanes per (b,d) channel, one state/lane.
// Time loop unrolled x8; all loads for the next 8 steps are issued up-front
// (h-independent addresses), then 8 serial recurrence steps run on registers.
// exp via exp2f on pre-scaled A (single v_exp_f32).
// Fuses y = (scan + u*D) * silu(z); emits y as bf16 for the MFMA out-GEMM.
// ---------------------------------------------------------------------------
#define SCAN_U 8
__global__ __launch_bounds__(256) void scan_kernel(
    const float* __restrict__ delta, // [B*L, DIN]
    const float* __restrict__ xc,    // [B*L, DIN]
    const float* __restrict__ dbc,   // [B*L, 96]: dt|B|C
    const float* __restrict__ xz,    // [B*L, 4096], z = cols DIN..
    const float* __restrict__ A_log, // [DIN, DS]
    const float* __restrict__ Dsk,   // [DIN]
    ushort_t* __restrict__ ybf,      // [B*L, DIN] bf16
    int reverse)
{
  const int tid = threadIdx.x;
  const int s = tid & 15;
  const int ch = blockIdx.x * 16 + (tid >> 4);  // 0..8191
  const int b = ch >> 11;
  const int d = ch & (DIN - 1);
  // exp(dl*As) = exp2(dl * As * log2(e))
  const float As2 = -expf(A_log[d * DS + s]) * 1.44269504088896f;
  const float Dv = Dsk[d];
  const int t0 = reverse ? (LL - 1) : 0;
  const int dt = reverse ? -1 : 1;
  const size_t rowbase = (size_t)b * LL;

  float h = 0.f;
  for (int i0 = 0; i0 < LL; i0 += SCAN_U) {
    float dl[SCAN_U], uu[SCAN_U], Bv[SCAN_U], Cv[SCAN_U], zz[SCAN_U];
#pragma unroll
    for (int k = 0; k < SCAN_U; ++k) {
      const size_t row = rowbase + (size_t)(t0 + dt * (i0 + k));
      dl[k] = delta[row * DIN + d];
      uu[k] = xc[row * DIN + d];
      Bv[k] = dbc[row * 96 + DR + s];
      Cv[k] = dbc[row * 96 + DR + DS + s];
      zz[k] = xz[row * 4096 + DIN + d];  // broadcast load (all 16 lanes)
    }
#pragma unroll
    for (int k = 0; k < SCAN_U; ++k) {
      float a = exp2f(dl[k] * As2);
      h = fmaf(h, a, (dl[k] * uu[k]) * Bv[k]);
      float p = h * Cv[k];
      p += __shfl_xor(p, 1, 16);
      p += __shfl_xor(p, 2, 16);
      p += __shfl_xor(p, 4, 16);
      p += __shfl_xor(p, 8, 16);
      if (s == 0) {
        const size_t row = rowbase + (size_t)(t0 + dt * (i0 + k));
        ybf[row * DIN + d] = f32_to_bf16((p + uu[k] * Dv) * silu_f(zz[k]));
      }
    }
  }
}

// LayerNorm over last dim (1024). One block per row.
__global__ __launch_bounds__(256) void ln_kernel(
    const float* __restrict__ x, const float* __restrict__ accum,
    const float* __restrict__ lnw, const float* __restrict__ lnb,
    float* __restrict__ out)
{
  int row = blockIdx.x;
  int tid = threadIdx.x;
  size_t base = (size_t)row * DD + tid * 4;
  float4 xv = *(const float4*)(x + base);
  float4 av = *(const float4*)(accum + base);
  float h0 = xv.x + av.x, h1 = xv.y + av.y;
  float h2 = xv.z + av.z, h3 = xv.w + av.w;
  float s = h0 + h1 + h2 + h3;
  float q = h0 * h0 + h1 * h1 + h2 * h2 + h3 * h3;
#pragma unroll
  for (int m = 1; m < 64; m <<= 1) {
    s += __shfl_xor(s, m, 64);
    q += __shfl_xor(q, m, 64);
  }
  __shared__ float rs[4], rq[4];
  int wid = tid >> 6;
  if ((tid & 63) == 0) { rs[wid] = s; rq[wid] = q; }
  __syncthreads();
  s = rs[0] + rs[1] + rs[2] + rs[3];
  q = rq[0] + rq[1] + rq[2] + rq[3];
  float mu = s * (1.f / DD);
  float var = q * (1.f / DD) - mu * mu;
  float rstd = rsqrtf(var + 1e-5f);
  float4 w  = *(const float4*)(lnw + tid * 4);
  float4 bv = *(const float4*)(lnb + tid * 4);
  float4 o;
  o.x = (h0 - mu) * rstd * w.x + bv.x;
  o.y = (h1 - mu) * rstd * w.y + bv.y;
  o.z = (h2 - mu) * rstd * w.z + bv.z;
  o.w = (h3 - mu) * rstd * w.w + bv.w;
  *(float4*)(out + base) = o;
}

extern "C" void kernel_launch(void* const* d_in, const int* in_sizes, int n_in,
                              void* d_out, int out_size, void* d_ws, size_t ws_size,
                              hipStream_t stream) {
  const float* x = (const float*)d_in[0];
  const float* P[2][9];
  for (int dir = 0; dir < 2; ++dir)
    for (int j = 0; j < 9; ++j)
      P[dir][j] = (const float*)d_in[1 + dir * 9 + j];
  const float* ln_w = (const float*)d_in[19];
  const float* ln_b = (const float*)d_in[20];
  float* out = (float*)d_out;
  (void)ws_size;

  // Workspace layout (floats). Total 44M floats = 176 MB.
  const size_t F = 1024 * 1024;
  float* ws      = (float*)d_ws;
  float*    XZ   = ws;                       // [4096,4096] f32  16M (xh|z)
  float*    XC   = ws + 16 * F;              // [4096,2048] f32   8M
  float*    DBC  = ws + 24 * F;              // [4096,96]   f32  (1M slot)
  float*    DELTA= ws + 25 * F;              // [4096,2048] f32   8M
  float*    ACC  = ws + 33 * F;              // [4096,1024] f32   4M
  ushort_t* XBF  = (ushort_t*)(ws + 37 * F); // [4096,1024] bf16 (2M f32)
  ushort_t* WBF  = (ushort_t*)(ws + 39 * F); // 8M ushort slot: in_proj_bf / YBF
  ushort_t* OPBF = (ushort_t*)(ws + 43 * F); // [1024,2048] bf16 (1M f32)

  const int MROWS = BB * LL;  // 4096

  // x -> bf16 once
  cast_bf16_kernel<<<(MROWS * DD) / 1024, 256, 0, stream>>>(x, XBF, MROWS * DD);

  for (int dir = 0; dir < 2; ++dir) {
    const float* in_proj  = P[dir][0];
    const float* conv_w   = P[dir][1];
    const float* conv_b   = P[dir][2];
    const float* x_proj   = P[dir][3];
    const float* dt_w     = P[dir][4];
    const float* dt_b     = P[dir][5];
    const float* A_log    = P[dir][6];
    const float* Dsk      = P[dir][7];
    const float* out_proj = P[dir][8];

    // weights -> bf16
    cast_bf16_kernel<<<(2 * DIN * DD) / 1024, 256, 0, stream>>>(
        in_proj, WBF, 2 * DIN * DD);
    cast_bf16_kernel<<<(DD * DIN) / 1024, 256, 0, stream>>>(
        out_proj, OPBF, DD * DIN);

    // xz = x @ in_proj.T : [4096,1024] x [4096,1024]^T -> [4096,4096]
    gemm_nt_mfma<EPI_STORE><<<dim3(32, 32), 256, 0, stream>>>(
        XBF, DD, WBF, DD, XZ, 2 * DIN, DD);

    // conv + silu
    conv_silu_kernel<<<(BB * LL * DIN) / 256, 256, 0, stream>>>(
        XZ, conv_w, conv_b, XC, dir);

    // dbc = xc @ x_proj.T : [4096,2048] x [96,2048]^T (f32)
    gemm_nt<EPI_STORE><<<dim3(32, 1), 256, 0, stream>>>(
        XC, DIN, x_proj, DIN, DBC, 96, nullptr, MROWS, DR + 2 * DS, DIN);

    // delta = softplus(dt @ dt_w.T + dt_b) : [4096,64] x [2048,64]^T (f32)
    gemm_nt<EPI_BIAS_SOFTPLUS><<<dim3(32, 16), 256, 0, stream>>>(
        DBC, 96, dt_w, DR, DELTA, DIN, dt_b, MROWS, DIN, DR);

    // selective scan + gating -> y (bf16) into WBF (in_proj_bf is dead)
    scan_kernel<<<512, 256, 0, stream>>>(
        DELTA, XC, DBC, XZ, A_log, Dsk, WBF, dir);

    // out accum (+)= y @ out_proj.T : [4096,2048] x [1024,2048]^T
    if (dir == 0)
      gemm_nt_mfma<EPI_STORE><<<dim3(32, 8), 256, 0, stream>>>(
          WBF, DIN, OPBF, DIN, ACC, DD, DIN);
    else
      gemm_nt_mfma<EPI_ADD><<<dim3(32, 8), 256, 0, stream>>>(
          WBF, DIN, OPBF, DIN, ACC, DD, DIN);
  }

  // LayerNorm(x + yf + yb)
  ln_kernel<<<MROWS, 256, 0, stream>>>(x, ACC, ln_w, ln_b, out);
}

// Round 8
// 1236.636 us; speedup vs baseline: 3.2370x; 1.4170x over previous
//
#include <hip/hip_runtime.h>
#include <cstdint>
#include <cstddef>

// Problem constants (match reference)
#define BB  4
#define LL  1024
#define DD  1024
#define DIN 2048   // d_inner
#define DS  16     // d_state
#define DC  4      // d_conv
#define DR  64     // dt_rank

typedef unsigned short ushort_t;
typedef __attribute__((ext_vector_type(8))) short bf16x8;
typedef __attribute__((ext_vector_type(4))) float f32x4;
typedef __attribute__((ext_vector_type(4))) unsigned short us4;

enum { EPI_STORE = 0, EPI_ADD = 1, EPI_BIAS_SOFTPLUS = 2 };

__device__ __forceinline__ float softplus_f(float v) {
  return (v > 20.f) ? v : log1pf(expf(v));
}
__device__ __forceinline__ float silu_f(float v) {
  return v / (1.f + expf(-v));
}
__device__ __forceinline__ ushort_t f32_to_bf16(float f) {
  uint32_t u = __float_as_uint(f);
  uint32_t r = (u + 0x7FFFu + ((u >> 16) & 1u)) >> 16;  // RNE
  return (ushort_t)r;
}
__device__ __forceinline__ float bf16_to_f32(ushort_t u) {
  return __uint_as_float(((uint32_t)u) << 16);
}

// async global->LDS, 16 bytes per lane (dest must be wave-uniform base + lane*16)
__device__ __forceinline__ void async_copy16(const void* g, void* lds) {
  __builtin_amdgcn_global_load_lds(
      (const __attribute__((address_space(1))) unsigned int*)g,
      (__attribute__((address_space(3))) unsigned int*)lds, 16, 0, 0);
}

// f32 -> bf16 cast, 4 elems/thread
__global__ __launch_bounds__(256) void cast_bf16_kernel(
    const float* __restrict__ src, ushort_t* __restrict__ dst, int n)
{
  int i = (blockIdx.x * 256 + threadIdx.x) * 4;
  if (i >= n) return;
  float4 v = *(const float4*)(src + i);
  us4 o = { f32_to_bf16(v.x), f32_to_bf16(v.y), f32_to_bf16(v.z), f32_to_bf16(v.w) };
  *(us4*)(dst + i) = o;
}

// f32 [srcRows, cols] -> bf16 [dstRows, cols], zero-fill rows >= srcRows
__global__ __launch_bounds__(256) void cast_pad_bf16_kernel(
    const float* __restrict__ src, ushort_t* __restrict__ dst,
    int srcRows, int dstRows, int cols)
{
  int i = (blockIdx.x * 256 + threadIdx.x) * 4;
  if (i >= dstRows * cols) return;
  int row = i / cols;
  us4 o = {0, 0, 0, 0};
  if (row < srcRows) {
    float4 v = *(const float4*)(src + (size_t)row * cols + (i % cols));
    o = (us4){ f32_to_bf16(v.x), f32_to_bf16(v.y), f32_to_bf16(v.z), f32_to_bf16(v.w) };
  }
  *(us4*)(dst + i) = o;
}

// ---------------------------------------------------------------------------
// bf16 MFMA GEMM (m97 structure): C[M,N] (+)= A[M,K] * B[N,K]^T
// A,B bf16 row-major (K contiguous), M,N multiples of 128, K of 32.
// OBF=1: store bf16; OBF=0: store f32. EPI_ADD/BIAS_SOFTPLUS are f32-out only.
// 128x128 tile, BK=32, 256 threads = 4 waves (2x2), 64x64 per wave.
// ---------------------------------------------------------------------------
template<int EPI, int OBF>
__global__ __launch_bounds__(256) void gemm_nt_mfma(
    const ushort_t* __restrict__ A, int lda,
    const ushort_t* __restrict__ B, int ldb,
    void* C, int ldc, const float* __restrict__ bias, int K)
{
  __shared__ __align__(16) ushort_t As[128 * 32];
  __shared__ __align__(16) ushort_t Bs[128 * 32];
  const int tid  = threadIdx.x;
  const int lane = tid & 63;
  const int wave = tid >> 6;            // 0..3
  const int wm = (wave & 1) * 64;
  const int wn = (wave >> 1) * 64;
  const int m0 = blockIdx.x * 128;
  const int n0 = blockIdx.y * 128;
  const int lr = lane & 15;             // fragment row within 16
  const int lk = (lane >> 4) * 8;       // fragment k offset (8 bf16 = 16 B)

  f32x4 acc[4][4];
#pragma unroll
  for (int i = 0; i < 4; ++i)
#pragma unroll
    for (int j = 0; j < 4; ++j) acc[i][j] = (f32x4){0.f, 0.f, 0.f, 0.f};

  for (int k0 = 0; k0 < K; k0 += 32) {
    __syncthreads();  // all waves done reading previous tile
    // stage 128x32 bf16 tiles of A and B: 512 chunks x 16 B each
#pragma unroll
    for (int it = 0; it < 2; ++it) {
      int c  = tid + it * 256;
      int r  = c >> 2;
      int cb = (c & 3) << 3;  // col offset in ushort units
      async_copy16(A + (size_t)(m0 + r) * lda + k0 + cb, (char*)As + c * 16);
      async_copy16(B + (size_t)(n0 + r) * ldb + k0 + cb, (char*)Bs + c * 16);
    }
    __syncthreads();  // vmcnt(0) drained by compiler -> tile ready

    bf16x8 a_frag[4], b_frag[4];
#pragma unroll
    for (int i = 0; i < 4; ++i)
      a_frag[i] = *(const bf16x8*)&As[(wm + i * 16 + lr) * 32 + lk];
#pragma unroll
    for (int j = 0; j < 4; ++j)
      b_frag[j] = *(const bf16x8*)&Bs[(wn + j * 16 + lr) * 32 + lk];
#pragma unroll
    for (int i = 0; i < 4; ++i)
#pragma unroll
      for (int j = 0; j < 4; ++j)
        acc[i][j] = __builtin_amdgcn_mfma_f32_16x16x32_bf16(
            a_frag[i], b_frag[j], acc[i][j], 0, 0, 0);
  }

  // C/D layout: row = (lane>>4)*4 + reg (1st operand dim), col = lane&15 (2nd)
  const int rbase = m0 + wm + (lane >> 4) * 4;
  const int cbase = n0 + wn + (lane & 15);
#pragma unroll
  for (int i = 0; i < 4; ++i)
#pragma unroll
    for (int j = 0; j < 4; ++j)
#pragma unroll
      for (int r = 0; r < 4; ++r) {
        size_t off = (size_t)(rbase + i * 16 + r) * ldc + cbase + j * 16;
        float v = acc[i][j][r];
        if (EPI == EPI_ADD) v += ((float*)C)[off];
        if (EPI == EPI_BIAS_SOFTPLUS) v = softplus_f(v + bias[cbase + j * 16]);
        if (OBF) ((ushort_t*)C)[off] = f32_to_bf16(v);
        else     ((float*)C)[off] = v;
      }
}

// Causal depthwise conv1d + bias + silu (bf16 in/out, f32 math).
// reverse=0: taps t-3+j w[j]; reverse=1: taps t+3-j w[j].
__global__ __launch_bounds__(256) void conv_silu_kernel(
    const ushort_t* __restrict__ xz,   // [B*L, 4096] bf16, xh = cols 0..DIN-1
    const float* __restrict__ w,       // [DIN, 4]
    const float* __restrict__ bias,    // [DIN]
    ushort_t* __restrict__ xc,         // [B*L, DIN] bf16
    int reverse)
{
  int idx = blockIdx.x * 256 + threadIdx.x;
  if (idx >= BB * LL * DIN) return;
  int d = idx & (DIN - 1);
  int t = (idx >> 11) & (LL - 1);
  int b = idx >> 21;
  const float4 wv = *(const float4*)(w + d * 4);
  const float wj[4] = {wv.x, wv.y, wv.z, wv.w};
  float acc = bias[d];
#pragma unroll
  for (int j = 0; j < 4; ++j) {
    int pos = reverse ? (t + 3 - j) : (t - 3 + j);
    if (pos >= 0 && pos < LL)
      acc = fmaf(bf16_to_f32(xz[(size_t)(b * LL + pos) * 4096 + d]), wj[j], acc);
  }
  xc[idx] = f32_to_bf16(silu_f(acc));
}

// ---------------------------------------------------------------------------
// Selective scan, ILP-unrolled x16: 16 lanes per (b,d) channel, 1 state/lane.
// All loads for the next 16 steps issued up-front (h-independent addresses),
// then 16 serial recurrence steps on registers. delta f32; u/B/C/z bf16.
// Fuses y = (scan + u*D) * silu(z); emits y as bf16 for the MFMA out-GEMM.
// ---------------------------------------------------------------------------
#define SCAN_U 16
__global__ __launch_bounds__(256) void scan_kernel(
    const float* __restrict__ delta,    // [B*L, DIN] f32
    const ushort_t* __restrict__ xcb,   // [B*L, DIN] bf16
    const ushort_t* __restrict__ dbc,   // [B*L, 128] bf16: dt|B|C|pad
    const ushort_t* __restrict__ xzb,   // [B*L, 4096] bf16, z = cols DIN..
    const float* __restrict__ A_log,    // [DIN, DS]
    const float* __restrict__ Dsk,      // [DIN]
    ushort_t* __restrict__ ybf,         // [B*L, DIN] bf16
    int reverse)
{
  const int tid = threadIdx.x;
  const int s = tid & 15;
  const int ch = blockIdx.x * 16 + (tid >> 4);  // 0..8191
  const int b = ch >> 11;
  const int d = ch & (DIN - 1);
  // exp(dl*As) = exp2(dl * As * log2(e))
  const float As2 = -expf(A_log[d * DS + s]) * 1.44269504088896f;
  const float Dv = Dsk[d];
  const int t0 = reverse ? (LL - 1) : 0;
  const int dt = reverse ? -1 : 1;
  const size_t rowbase = (size_t)b * LL;

  float h = 0.f;
  for (int i0 = 0; i0 < LL; i0 += SCAN_U) {
    float dl[SCAN_U], uu[SCAN_U], Bv[SCAN_U], Cv[SCAN_U], zz[SCAN_U];
#pragma unroll
    for (int k = 0; k < SCAN_U; ++k) {
      const size_t row = rowbase + (size_t)(t0 + dt * (i0 + k));
      dl[k] = delta[row * DIN + d];
      uu[k] = bf16_to_f32(xcb[row * DIN + d]);
      Bv[k] = bf16_to_f32(dbc[row * 128 + DR + s]);
      Cv[k] = bf16_to_f32(dbc[row * 128 + DR + DS + s]);
      zz[k] = bf16_to_f32(xzb[row * 4096 + DIN + d]);  // broadcast load
    }
#pragma unroll
    for (int k = 0; k < SCAN_U; ++k) {
      float a = exp2f(dl[k] * As2);
      h = fmaf(h, a, (dl[k] * uu[k]) * Bv[k]);
      float p = h * Cv[k];
      p += __shfl_xor(p, 1, 16);
      p += __shfl_xor(p, 2, 16);
      p += __shfl_xor(p, 4, 16);
      p += __shfl_xor(p, 8, 16);
      if (s == 0) {
        const size_t row = rowbase + (size_t)(t0 + dt * (i0 + k));
        ybf[row * DIN + d] = f32_to_bf16((p + uu[k] * Dv) * silu_f(zz[k]));
      }
    }
  }
}

// LayerNorm over last dim (1024). One block per row.
__global__ __launch_bounds__(256) void ln_kernel(
    const float* __restrict__ x, const float* __restrict__ accum,
    const float* __restrict__ lnw, const float* __restrict__ lnb,
    float* __restrict__ out)
{
  int row = blockIdx.x;
  int tid = threadIdx.x;
  size_t base = (size_t)row * DD + tid * 4;
  float4 xv = *(const float4*)(x + base);
  float4 av = *(const float4*)(accum + base);
  float h0 = xv.x + av.x, h1 = xv.y + av.y;
  float h2 = xv.z + av.z, h3 = xv.w + av.w;
  float s = h0 + h1 + h2 + h3;
  float q = h0 * h0 + h1 * h1 + h2 * h2 + h3 * h3;
#pragma unroll
  for (int m = 1; m < 64; m <<= 1) {
    s += __shfl_xor(s, m, 64);
    q += __shfl_xor(q, m, 64);
  }
  __shared__ float rs[4], rq[4];
  int wid = tid >> 6;
  if ((tid & 63) == 0) { rs[wid] = s; rq[wid] = q; }
  __syncthreads();
  s = rs[0] + rs[1] + rs[2] + rs[3];
  q = rq[0] + rq[1] + rq[2] + rq[3];
  float mu = s * (1.f / DD);
  float var = q * (1.f / DD) - mu * mu;
  float rstd = rsqrtf(var + 1e-5f);
  float4 w  = *(const float4*)(lnw + tid * 4);
  float4 bv = *(const float4*)(lnb + tid * 4);
  float4 o;
  o.x = (h0 - mu) * rstd * w.x + bv.x;
  o.y = (h1 - mu) * rstd * w.y + bv.y;
  o.z = (h2 - mu) * rstd * w.z + bv.z;
  o.w = (h3 - mu) * rstd * w.w + bv.w;
  *(float4*)(out + base) = o;
}

extern "C" void kernel_launch(void* const* d_in, const int* in_sizes, int n_in,
                              void* d_out, int out_size, void* d_ws, size_t ws_size,
                              hipStream_t stream) {
  const float* x = (const float*)d_in[0];
  const float* P[2][9];
  for (int dir = 0; dir < 2; ++dir)
    for (int j = 0; j < 9; ++j)
      P[dir][j] = (const float*)d_in[1 + dir * 9 + j];
  const float* ln_w = (const float*)d_in[19];
  const float* ln_b = (const float*)d_in[20];
  float* out = (float*)d_out;
  (void)ws_size;

  // Workspace layout (f32 slots, F = 1Mi). Total 38 F = 152 MB.
  const size_t F = 1024 * 1024;
  float* ws = (float*)d_ws;
  ushort_t* XZBF  = (ushort_t*)(ws);            // [4096,4096] bf16  (8F)
  ushort_t* XCBF  = (ushort_t*)(ws + 8  * F);   // [4096,2048] bf16  (4F)
  ushort_t* DBC   = (ushort_t*)(ws + 12 * F);   // [4096,128]  bf16  (0.5F slot)
  float*    DELTA = ws + 13 * F;                // [4096,2048] f32   (8F)
  float*    ACC   = ws + 21 * F;                // [4096,1024] f32   (4F)
  ushort_t* XBF   = (ushort_t*)(ws + 25 * F);   // [4096,1024] bf16  (2F)
  ushort_t* WBF   = (ushort_t*)(ws + 27 * F);   // [4096,1024] bf16  (4F) in_proj
  ushort_t* OPBF  = (ushort_t*)(ws + 31 * F);   // [1024,2048] bf16  (2F) out_proj
  ushort_t* XPBF  = (ushort_t*)(ws + 33 * F);   // [128,2048]  bf16  (0.5F) x_proj pad
  ushort_t* DTWBF = (ushort_t*)(ws + 33 * F + F / 2);  // [2048,64] bf16 (0.5F)
  ushort_t* YBF   = (ushort_t*)(ws + 34 * F);   // [4096,2048] bf16  (4F)

  const int MROWS = BB * LL;  // 4096

  // x -> bf16 once
  cast_bf16_kernel<<<(MROWS * DD) / 1024, 256, 0, stream>>>(x, XBF, MROWS * DD);

  for (int dir = 0; dir < 2; ++dir) {
    const float* in_proj  = P[dir][0];
    const float* conv_w   = P[dir][1];
    const float* conv_b   = P[dir][2];
    const float* x_proj   = P[dir][3];
    const float* dt_w     = P[dir][4];
    const float* dt_b     = P[dir][5];
    const float* A_log    = P[dir][6];
    const float* Dsk      = P[dir][7];
    const float* out_proj = P[dir][8];

    // weights -> bf16
    cast_bf16_kernel<<<(2 * DIN * DD) / 1024, 256, 0, stream>>>(
        in_proj, WBF, 2 * DIN * DD);
    cast_pad_bf16_kernel<<<(128 * DIN) / 1024, 256, 0, stream>>>(
        x_proj, XPBF, DR + 2 * DS, 128, DIN);
    cast_bf16_kernel<<<(DIN * DR) / 1024, 256, 0, stream>>>(
        dt_w, DTWBF, DIN * DR);

    // xz = x @ in_proj.T -> bf16 [4096, 4096]
    gemm_nt_mfma<EPI_STORE, 1><<<dim3(32, 32), 256, 0, stream>>>(
        XBF, DD, WBF, DD, XZBF, 2 * DIN, nullptr, DD);

    // conv + silu (bf16 in/out)
    conv_silu_kernel<<<(BB * LL * DIN) / 256, 256, 0, stream>>>(
        XZBF, conv_w, conv_b, XCBF, dir);

    // dbc = xc @ x_proj.T -> bf16 [4096, 128] (cols: dt|B|C|pad)
    gemm_nt_mfma<EPI_STORE, 1><<<dim3(32, 1), 256, 0, stream>>>(
        XCBF, DIN, XPBF, DIN, DBC, 128, nullptr, DIN);

    // delta = softplus(dt @ dt_w.T + dt_b) -> f32 [4096, 2048]
    gemm_nt_mfma<EPI_BIAS_SOFTPLUS, 0><<<dim3(32, 16), 256, 0, stream>>>(
        DBC, 128, DTWBF, DR, DELTA, DIN, dt_b, DR);

    // selective scan + gating -> y bf16
    scan_kernel<<<512, 256, 0, stream>>>(
        DELTA, XCBF, DBC, XZBF, A_log, Dsk, YBF, dir);

    // out accum (+)= y @ out_proj.T
    cast_bf16_kernel<<<(DD * DIN) / 1024, 256, 0, stream>>>(
        out_proj, OPBF, DD * DIN);
    if (dir == 0)
      gemm_nt_mfma<EPI_STORE, 0><<<dim3(32, 8), 256, 0, stream>>>(
          YBF, DIN, OPBF, DIN, ACC, DD, nullptr, DIN);
    else
      gemm_nt_mfma<EPI_ADD, 0><<<dim3(32, 8), 256, 0, stream>>>(
          YBF, DIN, OPBF, DIN, ACC, DD, nullptr, DIN);
  }

  // LayerNorm(x + yf + yb)
  ln_kernel<<<MROWS, 256, 0, stream>>>(x, ACC, ln_w, ln_b, out);
}

// Round 10
// 1106.397 us; speedup vs baseline: 3.6180x; 1.1177x over previous
//
#include <hip/hip_runtime.h>
#include <cstdint>
#include <cstddef>

// Problem constants (match reference)
#define BB  4
#define LL  1024
#define DD  1024
#define DIN 2048   // d_inner
#define DS  16     // d_state
#define DC  4      // d_conv
#define DR  64     // dt_rank

#define NCHUNK 8
#define CS (LL / NCHUNK)   // 128 steps per chunk

typedef unsigned short ushort_t;
typedef __attribute__((ext_vector_type(8))) short bf16x8;
typedef __attribute__((ext_vector_type(4))) float f32x4;
typedef __attribute__((ext_vector_type(4))) unsigned short us4;

enum { EPI_STORE = 0, EPI_ADD = 1, EPI_BIAS_SOFTPLUS = 2 };

__device__ __forceinline__ float softplus_f(float v) {
  return (v > 20.f) ? v : log1pf(expf(v));
}
__device__ __forceinline__ float silu_f(float v) {
  return v / (1.f + expf(-v));
}
__device__ __forceinline__ ushort_t f32_to_bf16(float f) {
  uint32_t u = __float_as_uint(f);
  uint32_t r = (u + 0x7FFFu + ((u >> 16) & 1u)) >> 16;  // RNE
  return (ushort_t)r;
}
__device__ __forceinline__ float bf16_to_f32(ushort_t u) {
  return __uint_as_float(((uint32_t)u) << 16);
}

// async global->LDS, 16 bytes per lane (dest must be wave-uniform base + lane*16)
__device__ __forceinline__ void async_copy16(const void* g, void* lds) {
  __builtin_amdgcn_global_load_lds(
      (const __attribute__((address_space(1))) unsigned int*)g,
      (__attribute__((address_space(3))) unsigned int*)lds, 16, 0, 0);
}

// f32 -> bf16 cast, 4 elems/thread
__global__ __launch_bounds__(256) void cast_bf16_kernel(
    const float* __restrict__ src, ushort_t* __restrict__ dst, int n)
{
  int i = (blockIdx.x * 256 + threadIdx.x) * 4;
  if (i >= n) return;
  float4 v = *(const float4*)(src + i);
  us4 o = { f32_to_bf16(v.x), f32_to_bf16(v.y), f32_to_bf16(v.z), f32_to_bf16(v.w) };
  *(us4*)(dst + i) = o;
}

// f32 [srcRows, cols] -> bf16 [dstRows, cols], zero-fill rows >= srcRows
__global__ __launch_bounds__(256) void cast_pad_bf16_kernel(
    const float* __restrict__ src, ushort_t* __restrict__ dst,
    int srcRows, int dstRows, int cols)
{
  int i = (blockIdx.x * 256 + threadIdx.x) * 4;
  if (i >= dstRows * cols) return;
  int row = i / cols;
  us4 o = {0, 0, 0, 0};
  if (row < srcRows) {
    float4 v = *(const float4*)(src + (size_t)row * cols + (i % cols));
    o = (us4){ f32_to_bf16(v.x), f32_to_bf16(v.y), f32_to_bf16(v.z), f32_to_bf16(v.w) };
  }
  *(us4*)(dst + i) = o;
}

// ---------------------------------------------------------------------------
// bf16 MFMA GEMM (m97 structure): C[M,N] (+)= A[M,K] * B[N,K]^T
// A,B bf16 row-major (K contiguous), M,N multiples of 128, K of 32.
// OBF=1: store bf16; OBF=0: store f32. EPI_ADD/BIAS_SOFTPLUS are f32-out only.
// 128x128 tile, BK=32, 256 threads = 4 waves (2x2), 64x64 per wave.
// ---------------------------------------------------------------------------
template<int EPI, int OBF>
__global__ __launch_bounds__(256) void gemm_nt_mfma(
    const ushort_t* __restrict__ A, int lda,
    const ushort_t* __restrict__ B, int ldb,
    void* C, int ldc, const float* __restrict__ bias, int K)
{
  __shared__ __align__(16) ushort_t As[128 * 32];
  __shared__ __align__(16) ushort_t Bs[128 * 32];
  const int tid  = threadIdx.x;
  const int lane = tid & 63;
  const int wave = tid >> 6;            // 0..3
  const int wm = (wave & 1) * 64;
  const int wn = (wave >> 1) * 64;
  const int m0 = blockIdx.x * 128;
  const int n0 = blockIdx.y * 128;
  const int lr = lane & 15;             // fragment row within 16
  const int lk = (lane >> 4) * 8;       // fragment k offset (8 bf16 = 16 B)

  f32x4 acc[4][4];
#pragma unroll
  for (int i = 0; i < 4; ++i)
#pragma unroll
    for (int j = 0; j < 4; ++j) acc[i][j] = (f32x4){0.f, 0.f, 0.f, 0.f};

  for (int k0 = 0; k0 < K; k0 += 32) {
    __syncthreads();  // all waves done reading previous tile
    // stage 128x32 bf16 tiles of A and B: 512 chunks x 16 B each
#pragma unroll
    for (int it = 0; it < 2; ++it) {
      int c  = tid + it * 256;
      int r  = c >> 2;
      int cb = (c & 3) << 3;  // col offset in ushort units
      async_copy16(A + (size_t)(m0 + r) * lda + k0 + cb, (char*)As + c * 16);
      async_copy16(B + (size_t)(n0 + r) * ldb + k0 + cb, (char*)Bs + c * 16);
    }
    __syncthreads();  // vmcnt(0) drained by compiler -> tile ready

    bf16x8 a_frag[4], b_frag[4];
#pragma unroll
    for (int i = 0; i < 4; ++i)
      a_frag[i] = *(const bf16x8*)&As[(wm + i * 16 + lr) * 32 + lk];
#pragma unroll
    for (int j = 0; j < 4; ++j)
      b_frag[j] = *(const bf16x8*)&Bs[(wn + j * 16 + lr) * 32 + lk];
#pragma unroll
    for (int i = 0; i < 4; ++i)
#pragma unroll
      for (int j = 0; j < 4; ++j)
        acc[i][j] = __builtin_amdgcn_mfma_f32_16x16x32_bf16(
            a_frag[i], b_frag[j], acc[i][j], 0, 0, 0);
  }

  // C/D layout: row = (lane>>4)*4 + reg (1st operand dim), col = lane&15 (2nd)
  const int rbase = m0 + wm + (lane >> 4) * 4;
  const int cbase = n0 + wn + (lane & 15);
#pragma unroll
  for (int i = 0; i < 4; ++i)
#pragma unroll
    for (int j = 0; j < 4; ++j)
#pragma unroll
      for (int r = 0; r < 4; ++r) {
        size_t off = (size_t)(rbase + i * 16 + r) * ldc + cbase + j * 16;
        float v = acc[i][j][r];
        if (EPI == EPI_ADD) v += ((float*)C)[off];
        if (EPI == EPI_BIAS_SOFTPLUS) v = softplus_f(v + bias[cbase + j * 16]);
        if (OBF) ((ushort_t*)C)[off] = f32_to_bf16(v);
        else     ((float*)C)[off] = v;
      }
}

// Causal depthwise conv1d + bias + silu (bf16 in/out, f32 math).
// reverse=0: taps t-3+j w[j]; reverse=1: taps t+3-j w[j].
__global__ __launch_bounds__(256) void conv_silu_kernel(
    const ushort_t* __restrict__ xz,   // [B*L, 4096] bf16, xh = cols 0..DIN-1
    const float* __restrict__ w,       // [DIN, 4]
    const float* __restrict__ bias,    // [DIN]
    ushort_t* __restrict__ xc,         // [B*L, DIN] bf16
    int reverse)
{
  int idx = blockIdx.x * 256 + threadIdx.x;
  if (idx >= BB * LL * DIN) return;
  int d = idx & (DIN - 1);
  int t = (idx >> 11) & (LL - 1);
  int b = idx >> 21;
  const float4 wv = *(const float4*)(w + d * 4);
  const float wj[4] = {wv.x, wv.y, wv.z, wv.w};
  float acc = bias[d];
#pragma unroll
  for (int j = 0; j < 4; ++j) {
    int pos = reverse ? (t + 3 - j) : (t - 3 + j);
    if (pos >= 0 && pos < LL)
      acc = fmaf(bf16_to_f32(xz[(size_t)(b * LL + pos) * 4096 + d]), wj[j], acc);
  }
  xc[idx] = f32_to_bf16(silu_f(acc));
}

// ---------------------------------------------------------------------------
// Chunked selective scan, pass A: per (channel, chunk) compute the chunk's
// state-transition summary with h0 = 0:  Aprod = prod(a_t), Hloc = local h.
// 16 lanes per channel (one state each). No cross-lane ops, 3 loads/step.
// Chunks are indexed in SCAN order (position p = chunk*CS + k; t = t0 + dt*p),
// so composition is direction-uniform.
// ---------------------------------------------------------------------------
__global__ __launch_bounds__(256) void scan_partial_kernel(
    const float* __restrict__ delta,    // [B*L, DIN] f32
    const ushort_t* __restrict__ xcb,   // [B*L, DIN] bf16
    const ushort_t* __restrict__ dbc,   // [B*L, 128] bf16: dt|B|C|pad
    const float* __restrict__ A_log,    // [DIN, DS]
    float* __restrict__ Asum,           // [8192, NCHUNK, 16]
    float* __restrict__ Hsum,           // [8192, NCHUNK, 16]
    int reverse)
{
  const int tid = threadIdx.x;
  const int s = tid & 15;
  const int ch = blockIdx.x * 16 + (tid >> 4);  // 0..8191
  const int cc = blockIdx.y;                    // chunk (scan order)
  const int b = ch >> 11;
  const int d = ch & (DIN - 1);
  const float As2 = -expf(A_log[d * DS + s]) * 1.44269504088896f;
  const int t0 = reverse ? (LL - 1) : 0;
  const int dt = reverse ? -1 : 1;
  const size_t rowbase = (size_t)b * LL;

  float h = 0.f, Ap = 1.f;
  for (int i0 = cc * CS; i0 < (cc + 1) * CS; i0 += 8) {
    float dl[8], uu[8], Bv[8];
#pragma unroll
    for (int k = 0; k < 8; ++k) {
      const size_t row = rowbase + (size_t)(t0 + dt * (i0 + k));
      dl[k] = delta[row * DIN + d];
      uu[k] = bf16_to_f32(xcb[row * DIN + d]);
      Bv[k] = bf16_to_f32(dbc[row * 128 + DR + s]);
    }
#pragma unroll
    for (int k = 0; k < 8; ++k) {
      float a = exp2f(dl[k] * As2);
      h = fmaf(h, a, (dl[k] * uu[k]) * Bv[k]);
      Ap *= a;
    }
  }
  const size_t off = ((size_t)ch * NCHUNK + cc) * 16 + s;
  Asum[off] = Ap;
  Hsum[off] = h;
}

// ---------------------------------------------------------------------------
// Chunked selective scan, pass B: compose incoming state from earlier chunks'
// summaries (<= NCHUNK-1 fmas), then scan this chunk emitting y.
// Fuses y = (C.h + u*D) * silu(z); emits y as bf16 for the MFMA out-GEMM.
// ---------------------------------------------------------------------------
__global__ __launch_bounds__(256) void scan_final_kernel(
    const float* __restrict__ delta,    // [B*L, DIN] f32
    const ushort_t* __restrict__ xcb,   // [B*L, DIN] bf16
    const ushort_t* __restrict__ dbc,   // [B*L, 128] bf16: dt|B|C|pad
    const ushort_t* __restrict__ xzb,   // [B*L, 4096] bf16, z = cols DIN..
    const float* __restrict__ A_log,    // [DIN, DS]
    const float* __restrict__ Dsk,      // [DIN]
    const float* __restrict__ Asum,     // [8192, NCHUNK, 16]
    const float* __restrict__ Hsum,     // [8192, NCHUNK, 16]
    ushort_t* __restrict__ ybf,         // [B*L, DIN] bf16
    int reverse)
{
  const int tid = threadIdx.x;
  const int s = tid & 15;
  const int ch = blockIdx.x * 16 + (tid >> 4);  // 0..8191
  const int cc = blockIdx.y;                    // chunk (scan order)
  const int b = ch >> 11;
  const int d = ch & (DIN - 1);
  const float As2 = -expf(A_log[d * DS + s]) * 1.44269504088896f;
  const float Dv = Dsk[d];
  const int t0 = reverse ? (LL - 1) : 0;
  const int dt = reverse ? -1 : 1;
  const size_t rowbase = (size_t)b * LL;

  // incoming state: fold earlier chunks (scan order)
  float h = 0.f;
  for (int c = 0; c < cc; ++c) {
    const size_t off = ((size_t)ch * NCHUNK + c) * 16 + s;
    h = fmaf(Asum[off], h, Hsum[off]);
  }

  for (int i0 = cc * CS; i0 < (cc + 1) * CS; i0 += 8) {
    float dl[8], uu[8], Bv[8], Cv[8], zz[8];
#pragma unroll
    for (int k = 0; k < 8; ++k) {
      const size_t row = rowbase + (size_t)(t0 + dt * (i0 + k));
      dl[k] = delta[row * DIN + d];
      uu[k] = bf16_to_f32(xcb[row * DIN + d]);
      Bv[k] = bf16_to_f32(dbc[row * 128 + DR + s]);
      Cv[k] = bf16_to_f32(dbc[row * 128 + DR + DS + s]);
      zz[k] = bf16_to_f32(xzb[row * 4096 + DIN + d]);  // broadcast load
    }
#pragma unroll
    for (int k = 0; k < 8; ++k) {
      float a = exp2f(dl[k] * As2);
      h = fmaf(h, a, (dl[k] * uu[k]) * Bv[k]);
      float p = h * Cv[k];
      p += __shfl_xor(p, 1, 16);
      p += __shfl_xor(p, 2, 16);
      p += __shfl_xor(p, 4, 16);
      p += __shfl_xor(p, 8, 16);
      if (s == 0) {
        const size_t row = rowbase + (size_t)(t0 + dt * (i0 + k));
        ybf[row * DIN + d] = f32_to_bf16((p + uu[k] * Dv) * silu_f(zz[k]));
      }
    }
  }
}

// LayerNorm over last dim (1024). One block per row.
__global__ __launch_bounds__(256) void ln_kernel(
    const float* __restrict__ x, const float* __restrict__ accum,
    const float* __restrict__ lnw, const float* __restrict__ lnb,
    float* __restrict__ out)
{
  int row = blockIdx.x;
  int tid = threadIdx.x;
  size_t base = (size_t)row * DD + tid * 4;
  float4 xv = *(const float4*)(x + base);
  float4 av = *(const float4*)(accum + base);
  float h0 = xv.x + av.x, h1 = xv.y + av.y;
  float h2 = xv.z + av.z, h3 = xv.w + av.w;
  float s = h0 + h1 + h2 + h3;
  float q = h0 * h0 + h1 * h1 + h2 * h2 + h3 * h3;
#pragma unroll
  for (int m = 1; m < 64; m <<= 1) {
    s += __shfl_xor(s, m, 64);
    q += __shfl_xor(q, m, 64);
  }
  __shared__ float rs[4], rq[4];
  int wid = tid >> 6;
  if ((tid & 63) == 0) { rs[wid] = s; rq[wid] = q; }
  __syncthreads();
  s = rs[0] + rs[1] + rs[2] + rs[3];
  q = rq[0] + rq[1] + rq[2] + rq[3];
  float mu = s * (1.f / DD);
  float var = q * (1.f / DD) - mu * mu;
  float rstd = rsqrtf(var + 1e-5f);
  float4 w  = *(const float4*)(lnw + tid * 4);
  float4 bv = *(const float4*)(lnb + tid * 4);
  float4 o;
  o.x = (h0 - mu) * rstd * w.x + bv.x;
  o.y = (h1 - mu) * rstd * w.y + bv.y;
  o.z = (h2 - mu) * rstd * w.z + bv.z;
  o.w = (h3 - mu) * rstd * w.w + bv.w;
  *(float4*)(out + base) = o;
}

extern "C" void kernel_launch(void* const* d_in, const int* in_sizes, int n_in,
                              void* d_out, int out_size, void* d_ws, size_t ws_size,
                              hipStream_t stream) {
  const float* x = (const float*)d_in[0];
  const float* P[2][9];
  for (int dir = 0; dir < 2; ++dir)
    for (int j = 0; j < 9; ++j)
      P[dir][j] = (const float*)d_in[1 + dir * 9 + j];
  const float* ln_w = (const float*)d_in[19];
  const float* ln_b = (const float*)d_in[20];
  float* out = (float*)d_out;
  (void)ws_size;

  // Workspace layout (f32 slots, F = 1Mi). Total 40 F = 160 MB.
  const size_t F = 1024 * 1024;
  float* ws = (float*)d_ws;
  ushort_t* XZBF  = (ushort_t*)(ws);            // [4096,4096] bf16  (8F)
  ushort_t* XCBF  = (ushort_t*)(ws + 8  * F);   // [4096,2048] bf16  (4F)
  ushort_t* DBC   = (ushort_t*)(ws + 12 * F);   // [4096,128]  bf16  (0.5F slot)
  float*    DELTA = ws + 13 * F;                // [4096,2048] f32   (8F)
  float*    ACC   = ws + 21 * F;                // [4096,1024] f32   (4F)
  ushort_t* XBF   = (ushort_t*)(ws + 25 * F);   // [4096,1024] bf16  (2F)
  ushort_t* WBF   = (ushort_t*)(ws + 27 * F);   // [4096,1024] bf16  (4F) in_proj
  ushort_t* OPBF  = (ushort_t*)(ws + 31 * F);   // [1024,2048] bf16  (2F) out_proj
  ushort_t* XPBF  = (ushort_t*)(ws + 33 * F);   // [128,2048]  bf16  (0.5F) x_proj pad
  ushort_t* DTWBF = (ushort_t*)(ws + 33 * F + F / 2);  // [2048,64] bf16 (0.5F)
  ushort_t* YBF   = (ushort_t*)(ws + 34 * F);   // [4096,2048] bf16  (4F)
  float*    ASUM  = ws + 38 * F;                // [8192,8,16] f32   (1F)
  float*    HSUM  = ws + 39 * F;                // [8192,8,16] f32   (1F)

  const int MROWS = BB * LL;  // 4096

  // x -> bf16 once
  cast_bf16_kernel<<<(MROWS * DD) / 1024, 256, 0, stream>>>(x, XBF, MROWS * DD);

  for (int dir = 0; dir < 2; ++dir) {
    const float* in_proj  = P[dir][0];
    const float* conv_w   = P[dir][1];
    const float* conv_b   = P[dir][2];
    const float* x_proj   = P[dir][3];
    const float* dt_w     = P[dir][4];
    const float* dt_b     = P[dir][5];
    const float* A_log    = P[dir][6];
    const float* Dsk      = P[dir][7];
    const float* out_proj = P[dir][8];

    // weights -> bf16
    cast_bf16_kernel<<<(2 * DIN * DD) / 1024, 256, 0, stream>>>(
        in_proj, WBF, 2 * DIN * DD);
    cast_pad_bf16_kernel<<<(128 * DIN) / 1024, 256, 0, stream>>>(
        x_proj, XPBF, DR + 2 * DS, 128, DIN);
    cast_bf16_kernel<<<(DIN * DR) / 1024, 256, 0, stream>>>(
        dt_w, DTWBF, DIN * DR);

    // xz = x @ in_proj.T -> bf16 [4096, 4096]
    gemm_nt_mfma<EPI_STORE, 1><<<dim3(32, 32), 256, 0, stream>>>(
        XBF, DD, WBF, DD, XZBF, 2 * DIN, nullptr, DD);

    // conv + silu (bf16 in/out)
    conv_silu_kernel<<<(BB * LL * DIN) / 256, 256, 0, stream>>>(
        XZBF, conv_w, conv_b, XCBF, dir);

    // dbc = xc @ x_proj.T -> bf16 [4096, 128] (cols: dt|B|C|pad)
    gemm_nt_mfma<EPI_STORE, 1><<<dim3(32, 1), 256, 0, stream>>>(
        XCBF, DIN, XPBF, DIN, DBC, 128, nullptr, DIN);

    // delta = softplus(dt @ dt_w.T + dt_b) -> f32 [4096, 2048]
    gemm_nt_mfma<EPI_BIAS_SOFTPLUS, 0><<<dim3(32, 16), 256, 0, stream>>>(
        DBC, 128, DTWBF, DR, DELTA, DIN, dt_b, DR);

    // chunked selective scan: pass A (summaries), pass B (compose + emit y)
    scan_partial_kernel<<<dim3(512, NCHUNK), 256, 0, stream>>>(
        DELTA, XCBF, DBC, A_log, ASUM, HSUM, dir);
    scan_final_kernel<<<dim3(512, NCHUNK), 256, 0, stream>>>(
        DELTA, XCBF, DBC, XZBF, A_log, Dsk, ASUM, HSUM, YBF, dir);

    // out accum (+)= y @ out_proj.T
    cast_bf16_kernel<<<(DD * DIN) / 1024, 256, 0, stream>>>(
        out_proj, OPBF, DD * DIN);
    if (dir == 0)
      gemm_nt_mfma<EPI_STORE, 0><<<dim3(32, 8), 256, 0, stream>>>(
          YBF, DIN, OPBF, DIN, ACC, DD, nullptr, DIN);
    else
      gemm_nt_mfma<EPI_ADD, 0><<<dim3(32, 8), 256, 0, stream>>>(
          YBF, DIN, OPBF, DIN, ACC, DD, nullptr, DIN);
  }

  // LayerNorm(x + yf + yb)
  ln_kernel<<<MROWS, 256, 0, stream>>>(x, ACC, ln_w, ln_b, out);
}